// Round 3
// baseline (462.576 us; speedup 1.0000x reference)
//
#include <hip/hip_runtime.h>
#include <math.h>

#define NB_ 512
#define B_ 32
#define H_ 16
#define D_ 576
#define KV_ 512
#define BS_ 128
#define SCALE_ 0.07216878364870323f   // 192^-0.5

typedef __attribute__((ext_vector_type(8))) short bf16x8;
typedef __attribute__((ext_vector_type(4))) float f32x4;

// Workspace as device globals: k1 fully writes before k2 reads, every call.
__device__ float g_o[NB_ * H_ * KV_];   // unscaled per-block output, 16.8 MB
__device__ float g_bm[NB_ * H_];        // per-block max
__device__ float g_bs[NB_ * H_];        // per-block sum

typedef const __attribute__((address_space(1))) void* gp_t;
typedef __attribute__((address_space(3))) void* lp_t;
typedef __attribute__((address_space(3))) char* l3p;   // LDS byte pointer

// async global->LDS, 16B per lane. LDS dest MUST be wave-uniform (goes through
// M0); hardware writes lane i at dest + i*16. Per-lane variation lives ONLY in
// the global source address (m104/m108).
static __device__ __forceinline__ void glds16(const float* g, l3p l) {
    __builtin_amdgcn_global_load_lds((gp_t)g, (lp_t)l, 16, 0, 0);
}

static __device__ __forceinline__ unsigned int cvtpk(float a, float b) {
    unsigned int r;
    asm("v_cvt_pk_bf16_f32 %0, %1, %2" : "=v"(r) : "v"(a), "v"(b));
    return r;
}

static __device__ __forceinline__ bf16x8 pack8(float4 a, float4 b) {
    union { unsigned int u[4]; bf16x8 v; } r;
    r.u[0] = cvtpk(a.x, a.y);
    r.u[1] = cvtpk(a.z, a.w);
    r.u[2] = cvtpk(b.x, b.y);
    r.u[3] = cvtpk(b.z, b.w);
    return r.v;
}

// One workgroup per block n. 256 threads = 4 waves. Grid = 512 = 2 WG/CU;
// LDS 74.25 KB/WG -> exactly 2 WG/CU. Layout (floats):
//   buf0 [0,8192)      32 KB   K-chunk f32 [128][64] (granule-XOR) / V-chunk [16][512]
//   buf1 [8192,16384)  32 KB   (double buffer)
//   p_s  [16384,18432)  8 KB   [16][128]
//   mred [18432,18496)  lred [18496,18560)
// Per K-chunk: issue next chunk's glds (wave-uniform dest slabs), ONE
// __syncthreads (drains current chunk), compute. glds flight overlaps the
// previous chunk's compute + the co-resident block's work (m97 structure).
__global__ __launch_bounds__(256, 2) void mla_block_kernel(
    const float* __restrict__ query,
    const float* __restrict__ key_cache,
    const float* __restrict__ block_bias,
    const int* __restrict__ block_list,
    const int* __restrict__ block_groups)
{
    __shared__ __align__(16) float smem[18560];
    float* p_s  = smem + 16384;
    float* mred = smem + 18432;
    float* lred = smem + 18496;

    const l3p lbase = (l3p)smem;            // addrspacecast of __shared__
    const float* bufp[2] = { smem, smem + 8192 };

    const int tid = threadIdx.x;
    const int n   = blockIdx.x;
    const int b   = block_groups[n];
    const float* K = key_cache + (long)block_list[n] * (BS_ * D_);
    const float* Q = query + (long)b * (H_ * D_);

    const int w    = tid >> 6;
    const int lane = tid & 63;
    const int a15  = lane & 15;
    const int q4   = lane >> 4;
    const int krow = lane >> 4;             // 0..3 within a 4-row slab
    const int kgc  = lane & 15;             // granule col within row

    // bias in regs (hoisted; consumed in epilogue)
    const float* bias = block_bias + n * BS_;
    const float b0 = bias[32 * w + a15];
    const float b1 = bias[32 * w + 16 + a15];

    // ---- issue K chunk 0 into buf0 (async, wave-uniform dest slabs) ----
    // wave w, call j: rows r0..r0+3 (r0 = w*32+j*4), 16 granules/row.
    // LDS slab = r0*256 bytes; lane L -> row r0+(L>>4), granule (L&15).
    // Global source pre-applies the XOR swizzle: granule (L&15)^(row&7).
#pragma unroll
    for (int j = 0; j < 8; ++j) {
        int row = w * 32 + j * 4 + krow;
        glds16(K + row * D_ + 4 * (kgc ^ (row & 7)),
               lbase + (w * 32 + j * 4) * 256);
    }

    // ---- q fragments straight to registers (unscaled; SCALE applied post-MFMA) ----
    bf16x8 af[9][2];
#pragma unroll
    for (int kk = 0; kk < 9; ++kk)
#pragma unroll
        for (int t = 0; t < 2; ++t) {
            const float* qp = Q + a15 * D_ + kk * 64 + t * 32 + 8 * q4;
            float4 qa = *(const float4*)qp;
            float4 qb = *(const float4*)(qp + 4);
            af[kk][t] = pack8(qa, qb);
        }

    // ---- phase 1: QK^T, double-buffered ----
    f32x4 acc0 = {0.f, 0.f, 0.f, 0.f};
    f32x4 acc1 = {0.f, 0.f, 0.f, 0.f};
    const int s0  = 32 * w + a15;
    const int key = a15 & 7;                // (s0&7) == ((s0+16)&7) == a15&7

#pragma unroll
    for (int kk = 0; kk < 9; ++kk) {
        __syncthreads();   // chunk kk resident; reads of buf[(kk+1)&1] (chunk kk-1) done
        if (kk < 8) {                       // stage next K chunk into buf^1
#pragma unroll
            for (int j = 0; j < 8; ++j) {
                int row = w * 32 + j * 4 + krow;
                glds16(K + row * D_ + (kk + 1) * 64 + 4 * (kgc ^ (row & 7)),
                       lbase + ((kk + 1) & 1) * 32768 + (w * 32 + j * 4) * 256);
            }
        } else {                            // stage V chunk 0 into buf1
            // wave w, call j: 64 granules starting at flat0=(w*8+j)*64;
            // lane L -> flat = flat0+L; row = flat>>7, col granule = flat&127.
#pragma unroll
            for (int j = 0; j < 8; ++j) {
                int fl = (w * 8 + j) * 64 + lane;
                glds16(K + (fl >> 7) * D_ + 4 * (fl & 127),
                       lbase + 32768 + (w * 8 + j) * 1024);
            }
        }
        const float* bk = bufp[kk & 1];
#pragma unroll
        for (int t = 0; t < 2; ++t) {
            int g0 = t * 8 + 2 * q4;
            float4 a0 = *(const float4*)(bk + s0 * 64        + 4 * ((g0    ) ^ key));
            float4 a1 = *(const float4*)(bk + s0 * 64        + 4 * ((g0 + 1) ^ key));
            float4 c0 = *(const float4*)(bk + (s0 + 16) * 64 + 4 * ((g0    ) ^ key));
            float4 c1 = *(const float4*)(bk + (s0 + 16) * 64 + 4 * ((g0 + 1) ^ key));
            acc0 = __builtin_amdgcn_mfma_f32_16x16x32_bf16(af[kk][t], pack8(a0, a1), acc0, 0, 0, 0);
            acc1 = __builtin_amdgcn_mfma_f32_16x16x32_bf16(af[kk][t], pack8(c0, c1), acc1, 0, 0, 0);
        }
    }

    // ---- softmax epilogue. C layout: col(s)=lane&15, row(h)=q4*4+r ----
    float lg0[4], lg1[4], mw[4];
#pragma unroll
    for (int r = 0; r < 4; ++r) {
        lg0[r] = SCALE_ * acc0[r] + b0;
        lg1[r] = SCALE_ * acc1[r] + b1;
        float m = fmaxf(lg0[r], lg1[r]);
#pragma unroll
        for (int off = 1; off < 16; off <<= 1) m = fmaxf(m, __shfl_xor(m, off));
        mw[r] = m;
    }
    if (a15 == 0) {
#pragma unroll
        for (int r = 0; r < 4; ++r) mred[w * 16 + 4 * q4 + r] = mw[r];
    }
    __syncthreads();                        // mred visible (also drains V0 glds)
    float mg[4], lw[4];
#pragma unroll
    for (int r = 0; r < 4; ++r) {
        int h = 4 * q4 + r;
        float m = fmaxf(fmaxf(mred[h], mred[16 + h]), fmaxf(mred[32 + h], mred[48 + h]));
        mg[r] = m;
        float p0 = __expf(lg0[r] - m);
        float p1 = __expf(lg1[r] - m);
        p_s[h * BS_ + 32 * w + a15]      = p0;
        p_s[h * BS_ + 32 * w + 16 + a15] = p1;
        float s = p0 + p1;
#pragma unroll
        for (int off = 1; off < 16; off <<= 1) s += __shfl_xor(s, off);
        lw[r] = s;
    }
    if (a15 == 0) {
#pragma unroll
        for (int r = 0; r < 4; ++r) lred[w * 16 + 4 * q4 + r] = lw[r];
    }
    __syncthreads();                        // p_s + lred visible
    if (w == 0 && a15 == 0) {
#pragma unroll
        for (int r = 0; r < 4; ++r) {
            int h = 4 * q4 + r;
            g_bm[n * H_ + h] = mg[r];
            g_bs[n * H_ + h] = lred[h] + lred[16 + h] + lred[32 + h] + lred[48 + h];
        }
    }

    // ---- phase 2: o = p @ V, V f32 in 16-row chunks, double-buffered ----
    // V chunk sc lives in buf[(sc+1)&1]; V0 already staged into buf1 above.
    const int hg = w;
    const int sl = lane;
    float4 oa0[4], oa1[4];
#pragma unroll
    for (int i = 0; i < 4; ++i) {
        oa0[i] = make_float4(0.f, 0.f, 0.f, 0.f);
        oa1[i] = make_float4(0.f, 0.f, 0.f, 0.f);
    }
#pragma unroll
    for (int sc = 0; sc < 8; ++sc) {
        __syncthreads();   // V_sc resident; reads of buf[sc&1] (V_{sc-1}) done
        if (sc < 7) {                       // stage next V chunk into buf[sc&1]
#pragma unroll
            for (int j = 0; j < 8; ++j) {
                int fl = (w * 8 + j) * 64 + lane;
                glds16(K + (long)(16 * (sc + 1) + (fl >> 7)) * D_ + 4 * (fl & 127),
                       lbase + (sc & 1) * 32768 + (w * 8 + j) * 1024);
            }
        }
        const float* bv = bufp[(sc + 1) & 1];
#pragma unroll
        for (int sg = 0; sg < 4; ++sg) {
            float4 pv[4];
#pragma unroll
            for (int i = 0; i < 4; ++i)     // uniform-address broadcast float4
                pv[i] = *(const float4*)(p_s + (4 * hg + i) * BS_ + 16 * sc + 4 * sg);
#pragma unroll
            for (int ss = 0; ss < 4; ++ss) {
                const int s = 4 * sg + ss;
                float4 v0 = *(const float4*)(bv + s * KV_ + 4 * sl);
                float4 v1 = *(const float4*)(bv + s * KV_ + 256 + 4 * sl);
#pragma unroll
                for (int i = 0; i < 4; ++i) {
                    const float p = ss == 0 ? pv[i].x : ss == 1 ? pv[i].y
                                  : ss == 2 ? pv[i].z : pv[i].w;
                    oa0[i].x += p * v0.x; oa0[i].y += p * v0.y;
                    oa0[i].z += p * v0.z; oa0[i].w += p * v0.w;
                    oa1[i].x += p * v1.x; oa1[i].y += p * v1.y;
                    oa1[i].z += p * v1.z; oa1[i].w += p * v1.w;
                }
            }
        }
    }

    // ---- write unscaled o ----
    float* op = g_o + (long)n * H_ * KV_;
#pragma unroll
    for (int i = 0; i < 4; ++i) {
        *(float4*)(op + (4 * hg + i) * KV_ + 4 * sl)       = oa0[i];
        *(float4*)(op + (4 * hg + i) * KV_ + 256 + 4 * sl) = oa1[i];
    }
}

// Group combine: 2 WGs per (b,h) (column halves) for better latency hiding.
// 1024 WGs x 128 threads; within a WG, wave0 handles j=0..7, wave1 j=8..15.
__global__ __launch_bounds__(128) void mla_combine_kernel(float* __restrict__ out)
{
    const int gid  = blockIdx.x;            // 0..1023
    const int bh   = gid >> 1;
    const int half = gid & 1;
    const int b = bh >> 4;
    const int h = bh & 15;
    const int tid = threadIdx.x;
    const int c4 = tid & 63;                // float4 index within 256-col half
    const int jh = tid >> 6;                // 0/1 — wave-uniform j-subset

    float bm[16];
    float m = -1e30f;
#pragma unroll
    for (int j = 0; j < 16; ++j) {
        bm[j] = g_bm[(16 * b + j) * H_ + h];
        m = fmaxf(m, bm[j]);
    }
    float sa[16];
    float gs = 0.f;
#pragma unroll
    for (int j = 0; j < 16; ++j) {
        sa[j] = g_bs[(16 * b + j) * H_ + h] * __expf(bm[j] - m);
        gs += sa[j];
    }

    float4 acc = make_float4(0.f, 0.f, 0.f, 0.f);
    if (jh == 0) {
#pragma unroll
        for (int j = 0; j < 8; ++j) {
            float r = __expf(bm[j] - m) / fmaxf(gs, sa[j]);
            const float4 v = *(const float4*)(g_o + ((long)((16 * b + j) * H_ + h)) * KV_
                                              + half * 256 + 4 * c4);
            acc.x += r * v.x; acc.y += r * v.y; acc.z += r * v.z; acc.w += r * v.w;
        }
    } else {
#pragma unroll
        for (int j = 8; j < 16; ++j) {
            float r = __expf(bm[j] - m) / fmaxf(gs, sa[j]);
            const float4 v = *(const float4*)(g_o + ((long)((16 * b + j) * H_ + h)) * KV_
                                              + half * 256 + 4 * c4);
            acc.x += r * v.x; acc.y += r * v.y; acc.z += r * v.z; acc.w += r * v.w;
        }
    }
    __shared__ float4 red[64];
    if (jh) red[c4] = acc;
    __syncthreads();
    if (!jh) {
        float4 o2 = red[c4];
        acc.x += o2.x; acc.y += o2.y; acc.z += o2.z; acc.w += o2.w;
        *(float4*)(out + (long)bh * KV_ + half * 256 + 4 * c4) = acc;
    }
}

extern "C" void kernel_launch(void* const* d_in, const int* in_sizes, int n_in,
                              void* d_out, int out_size, void* d_ws, size_t ws_size,
                              hipStream_t stream)
{
    const float* query        = (const float*)d_in[0];
    const float* key_cache    = (const float*)d_in[1];
    // d_in[2] = block_mapping (one-hot of block_groups) — not needed
    const float* block_bias   = (const float*)d_in[3];
    const int*   block_list   = (const int*)d_in[4];
    const int*   block_groups = (const int*)d_in[5];
    float* out = (float*)d_out;

    mla_block_kernel<<<NB_, 256, 0, stream>>>(query, key_cache, block_bias,
                                              block_list, block_groups);
    mla_combine_kernel<<<B_ * H_ * 2, 128, 0, stream>>>(out);
}

// Round 4
// 411.608 us; speedup vs baseline: 1.1238x; 1.1238x over previous
//
#include <hip/hip_runtime.h>
#include <math.h>

#define NB_ 512
#define B_ 32
#define H_ 16
#define D_ 576
#define KV_ 512
#define BS_ 128
#define SCALE_ 0.07216878364870323f   // 192^-0.5

typedef __attribute__((ext_vector_type(8))) short bf16x8;
typedef __attribute__((ext_vector_type(4))) float f32x4;

// Workspace as device globals: k1 fully writes before k2 reads, every call.
__device__ float g_o[NB_ * H_ * KV_];   // unscaled per-block output, 16.8 MB
__device__ float g_bm[NB_ * H_];        // per-block max
__device__ float g_bs[NB_ * H_];        // per-block sum

static __device__ __forceinline__ unsigned int cvtpk(float a, float b) {
    unsigned int r;
    asm("v_cvt_pk_bf16_f32 %0, %1, %2" : "=v"(r) : "v"(a), "v"(b));
    return r;
}

static __device__ __forceinline__ bf16x8 pack8(float4 a, float4 b) {
    union { unsigned int u[4]; bf16x8 v; } r;
    r.u[0] = cvtpk(a.x, a.y);
    r.u[1] = cvtpk(a.z, a.w);
    r.u[2] = cvtpk(b.x, b.y);
    r.u[3] = cvtpk(b.z, b.w);
    return r.v;
}

// One workgroup per block n. 256 threads = 4 waves, 2 WG/CU (grid 512).
// NO K/V LDS staging: every K/V element is consumed by exactly one lane of one
// fragment (zero cross-lane reuse), so MFMA A/B fragments and phase-2 V rows
// are loaded DIRECTLY from global (each fragment = 32 B contiguous; 4 lanes
// cover one 128-B line -> fully coalesced). f32->bf16 via v_cvt_pk in-reg.
// LDS holds only p_s (16x128) + reductions. Exactly 2 barriers per block.
__global__ __launch_bounds__(256, 2) void mla_block_kernel(
    const float* __restrict__ query,
    const float* __restrict__ key_cache,
    const float* __restrict__ block_bias,
    const int* __restrict__ block_list,
    const int* __restrict__ block_groups)
{
    __shared__ __align__(16) float p_s[H_ * BS_];   // 8 KB
    __shared__ float mred[64];
    __shared__ float lred[64];

    const int tid = threadIdx.x;
    const int n   = blockIdx.x;
    const int b   = block_groups[n];
    const float* K = key_cache + (long)block_list[n] * (BS_ * D_);
    const float* Q = query + (long)b * (H_ * D_);

    const int w    = tid >> 6;
    const int lane = tid & 63;
    const int a15  = lane & 15;
    const int q4   = lane >> 4;

    // bias in regs (consumed in epilogue)
    const float* bias = block_bias + n * BS_;
    const float b0 = bias[32 * w + a15];
    const float b1 = bias[32 * w + 16 + a15];

    // per-lane fragment bases; all 9x2 loads are immediate offsets off these
    const float* Qf  = Q + a15 * D_ + 8 * q4;               // A: q row a15
    const float* Kf0 = K + (32 * w + a15) * D_ + 8 * q4;    // B: K row s0
    const float* Kf1 = Kf0 + 16 * D_;                       // B: K row s0+16

    // ---- phase 1: QK^T straight from global ----
    f32x4 acc0 = {0.f, 0.f, 0.f, 0.f};
    f32x4 acc1 = {0.f, 0.f, 0.f, 0.f};
#pragma unroll
    for (int kk = 0; kk < 9; ++kk) {
#pragma unroll
        for (int t = 0; t < 2; ++t) {
            const int off = kk * 64 + t * 32;
            float4 qa = *(const float4*)(Qf  + off);
            float4 qb = *(const float4*)(Qf  + off + 4);
            float4 k0a = *(const float4*)(Kf0 + off);
            float4 k0b = *(const float4*)(Kf0 + off + 4);
            float4 k1a = *(const float4*)(Kf1 + off);
            float4 k1b = *(const float4*)(Kf1 + off + 4);
            bf16x8 a  = pack8(qa, qb);
            bf16x8 f0 = pack8(k0a, k0b);
            bf16x8 f1 = pack8(k1a, k1b);
            acc0 = __builtin_amdgcn_mfma_f32_16x16x32_bf16(a, f0, acc0, 0, 0, 0);
            acc1 = __builtin_amdgcn_mfma_f32_16x16x32_bf16(a, f1, acc1, 0, 0, 0);
        }
    }

    // ---- softmax epilogue. C layout: col(s)=lane&15, row(h)=q4*4+r ----
    float lg0[4], lg1[4], mw[4];
#pragma unroll
    for (int r = 0; r < 4; ++r) {
        lg0[r] = SCALE_ * acc0[r] + b0;
        lg1[r] = SCALE_ * acc1[r] + b1;
        float m = fmaxf(lg0[r], lg1[r]);
#pragma unroll
        for (int off = 1; off < 16; off <<= 1) m = fmaxf(m, __shfl_xor(m, off));
        mw[r] = m;
    }
    if (a15 == 0) {
#pragma unroll
        for (int r = 0; r < 4; ++r) mred[w * 16 + 4 * q4 + r] = mw[r];
    }
    __syncthreads();                        // mred visible
    float mg[4], lw[4];
#pragma unroll
    for (int r = 0; r < 4; ++r) {
        int h = 4 * q4 + r;
        float m = fmaxf(fmaxf(mred[h], mred[16 + h]), fmaxf(mred[32 + h], mred[48 + h]));
        mg[r] = m;
        float p0 = __expf(lg0[r] - m);
        float p1 = __expf(lg1[r] - m);
        p_s[h * BS_ + 32 * w + a15]      = p0;
        p_s[h * BS_ + 32 * w + 16 + a15] = p1;
        float s = p0 + p1;
#pragma unroll
        for (int off = 1; off < 16; off <<= 1) s += __shfl_xor(s, off);
        lw[r] = s;
    }
    if (a15 == 0) {
#pragma unroll
        for (int r = 0; r < 4; ++r) lred[w * 16 + 4 * q4 + r] = lw[r];
    }
    __syncthreads();                        // p_s + lred visible
    if (w == 0 && a15 == 0) {
#pragma unroll
        for (int r = 0; r < 4; ++r) {
            int h = 4 * q4 + r;
            g_bm[n * H_ + h] = mg[r];
            g_bs[n * H_ + h] = lred[h] + lred[16 + h] + lred[32 + h] + lred[48 + h];
        }
    }

    // ---- phase 2: o = p @ V, V rows DIRECT from global (L2/L3-warm) ----
    // wave w owns heads 4w..4w+3; lane sl covers cols 4*sl and 256+4*sl.
    const int hg = w;
    const int sl = lane;
    float4 oa0[4], oa1[4];
#pragma unroll
    for (int i = 0; i < 4; ++i) {
        oa0[i] = make_float4(0.f, 0.f, 0.f, 0.f);
        oa1[i] = make_float4(0.f, 0.f, 0.f, 0.f);
    }
    const float* Vb = K + 4 * sl;
#pragma unroll 4
    for (int s4 = 0; s4 < 32; ++s4) {       // 4 s-rows per iteration
        float4 pv[4];
#pragma unroll
        for (int i = 0; i < 4; ++i)         // uniform-address broadcast float4
            pv[i] = *(const float4*)(p_s + (4 * hg + i) * BS_ + 4 * s4);
#pragma unroll
        for (int ss = 0; ss < 4; ++ss) {
            const int s = 4 * s4 + ss;
            float4 v0 = *(const float4*)(Vb + (long)s * D_);
            float4 v1 = *(const float4*)(Vb + (long)s * D_ + 256);
#pragma unroll
            for (int i = 0; i < 4; ++i) {
                const float p = ss == 0 ? pv[i].x : ss == 1 ? pv[i].y
                              : ss == 2 ? pv[i].z : pv[i].w;
                oa0[i].x += p * v0.x; oa0[i].y += p * v0.y;
                oa0[i].z += p * v0.z; oa0[i].w += p * v0.w;
                oa1[i].x += p * v1.x; oa1[i].y += p * v1.y;
                oa1[i].z += p * v1.z; oa1[i].w += p * v1.w;
            }
        }
    }

    // ---- write unscaled o ----
    float* op = g_o + (long)n * H_ * KV_;
#pragma unroll
    for (int i = 0; i < 4; ++i) {
        *(float4*)(op + (4 * hg + i) * KV_ + 4 * sl)       = oa0[i];
        *(float4*)(op + (4 * hg + i) * KV_ + 256 + 4 * sl) = oa1[i];
    }
}

// Group combine: 2 WGs per (b,h) (column halves). 1024 WGs x 128 threads;
// within a WG, wave0 handles j=0..7, wave1 j=8..15, LDS-reduce at the end.
__global__ __launch_bounds__(128) void mla_combine_kernel(float* __restrict__ out)
{
    const int gid  = blockIdx.x;            // 0..1023
    const int bh   = gid >> 1;
    const int half = gid & 1;
    const int b = bh >> 4;
    const int h = bh & 15;
    const int tid = threadIdx.x;
    const int c4 = tid & 63;                // float4 index within 256-col half
    const int jh = tid >> 6;                // 0/1 — wave-uniform j-subset

    float bm[16];
    float m = -1e30f;
#pragma unroll
    for (int j = 0; j < 16; ++j) {
        bm[j] = g_bm[(16 * b + j) * H_ + h];
        m = fmaxf(m, bm[j]);
    }
    float sa[16];
    float gs = 0.f;
#pragma unroll
    for (int j = 0; j < 16; ++j) {
        sa[j] = g_bs[(16 * b + j) * H_ + h] * __expf(bm[j] - m);
        gs += sa[j];
    }

    float4 acc = make_float4(0.f, 0.f, 0.f, 0.f);
    if (jh == 0) {
#pragma unroll
        for (int j = 0; j < 8; ++j) {
            float r = __expf(bm[j] - m) / fmaxf(gs, sa[j]);
            const float4 v = *(const float4*)(g_o + ((long)((16 * b + j) * H_ + h)) * KV_
                                              + half * 256 + 4 * c4);
            acc.x += r * v.x; acc.y += r * v.y; acc.z += r * v.z; acc.w += r * v.w;
        }
    } else {
#pragma unroll
        for (int j = 8; j < 16; ++j) {
            float r = __expf(bm[j] - m) / fmaxf(gs, sa[j]);
            const float4 v = *(const float4*)(g_o + ((long)((16 * b + j) * H_ + h)) * KV_
                                              + half * 256 + 4 * c4);
            acc.x += r * v.x; acc.y += r * v.y; acc.z += r * v.z; acc.w += r * v.w;
        }
    }
    __shared__ float4 red[64];
    if (jh) red[c4] = acc;
    __syncthreads();
    if (!jh) {
        float4 o2 = red[c4];
        acc.x += o2.x; acc.y += o2.y; acc.z += o2.z; acc.w += o2.w;
        *(float4*)(out + (long)bh * KV_ + half * 256 + 4 * c4) = acc;
    }
}

extern "C" void kernel_launch(void* const* d_in, const int* in_sizes, int n_in,
                              void* d_out, int out_size, void* d_ws, size_t ws_size,
                              hipStream_t stream)
{
    const float* query        = (const float*)d_in[0];
    const float* key_cache    = (const float*)d_in[1];
    // d_in[2] = block_mapping (one-hot of block_groups) — not needed
    const float* block_bias   = (const float*)d_in[3];
    const int*   block_list   = (const int*)d_in[4];
    const int*   block_groups = (const int*)d_in[5];
    float* out = (float*)d_out;

    mla_block_kernel<<<NB_, 256, 0, stream>>>(query, key_cache, block_bias,
                                              block_list, block_groups);
    mla_combine_kernel<<<B_ * H_ * 2, 128, 0, stream>>>(out);
}